// Round 19
// baseline (582.845 us; speedup 1.0000x reference)
//
#include <hip/hip_runtime.h>
#include <hip/hip_bf16.h>
#include <cstdint>
#include <cstddef>

#define N_TOK 8192
#define DIM   2048
#define HID   2048
#define NE    8
#define ARENA 18432   // >= 16384 + 8*127 padded rows (pad granularity 128)
#define NJOBS 2176    // >= sum_e ceil(cnt_e/128)*16  (<= 136*16)

typedef _Float16 half8  __attribute__((ext_vector_type(8)));
typedef _Float16 half4v __attribute__((ext_vector_type(4)));
typedef float    floatx4 __attribute__((ext_vector_type(4)));

#define BARR  __builtin_amdgcn_s_barrier()
#define LGKM0 asm volatile("s_waitcnt lgkmcnt(0)" ::: "memory")
#define VMC0  asm volatile("s_waitcnt vmcnt(0)" ::: "memory")

__device__ inline void gload_lds16(const void* g, void* l) {
    __builtin_amdgcn_global_load_lds(
        (const __attribute__((address_space(1))) unsigned int*)g,
        (__attribute__((address_space(3))) unsigned int*)l, 16, 0, 0);
}

__device__ __forceinline__ floatx4 MF(half8 a, half8 b, floatx4 c) {
    return __builtin_amdgcn_mfma_f32_16x16x32_f16(a, b, c, 0, 0, 0);
}

// ========== merged gate (two-pass 32KB LDS) + prep(W1 transpose->fp16) ==========
// blocks [0,512): gate — Wg staged in TWO 1024-dim halves (32 KB wgs) so the
//   merged kernel's static LDS is 32.8 KB, not 65.6 KB.  Per-token fp64
//   accumulation order is d-ascending in the same 4-dim groups as R13-R17 ->
//   bit-identical logits -> identical routing.  (R18's register gate lost to
//   uncoalesced 128B-stride Wg reads; R17's 64KB gate LDS capped prep at 2/CU.)
// blocks [512,8704): transpose W1 [E][R][C] fp32 -> [E][C][R] fp16 — now 4
//   blocks/CU resident (32.8 KB < 40 KB) -> full-rate HBM streaming.
__global__ __launch_bounds__(256, 4) void k_prep_gate(
        const float* __restrict__ W1, _Float16* __restrict__ w1t,
        const float* __restrict__ x, const float* __restrict__ Wg,
        const float* __restrict__ bg, _Float16* __restrict__ xh,
        int* __restrict__ te, float* __restrict__ tw, int* __restrict__ counts) {
    __shared__ __align__(16) char smem[32800];
    int b = blockIdx.x;
    if (b >= 512) {
        // ---------------- prep W1 ----------------
        float (*tile)[65] = (float (*)[65])smem;   // 16.6 KB of the 32.8
        int bb = b - 512;
        int e = bb >> 10, rem = bb & 1023;
        int r0 = (rem >> 5) * 64, c0 = (rem & 31) * 64;
        int tc = threadIdx.x & 63, tr = threadIdx.x >> 6;   // tr 0..3
        const float* ip = W1 + ((size_t)e * 2048 + r0) * 2048 + c0;
#pragma unroll
        for (int i = 0; i < 16; i++)
            tile[tr + i * 4][tc] = ip[(size_t)(tr + i * 4) * 2048 + tc];
        __syncthreads();
        _Float16* op = w1t + ((size_t)e * 2048 + c0) * 2048 + r0;
#pragma unroll
        for (int i = 0; i < 16; i++) {
            int cc = tr + i * 4;
            op[(size_t)cc * 2048 + tc] = (_Float16)tile[tc][cc];
        }
        return;
    }
    // ---------------- gate (two-pass over d halves) ----------------
    float* wgs = (float*)smem;              // [8][1024] for current half
    int* lcnt  = (int*)(smem + 32768);
    if (threadIdx.x < NE) lcnt[threadIdx.x] = 0;
    int wv = threadIdx.x >> 6, l = threadIdx.x & 63;
    int tbase = b * 16 + wv * 4;
    double acc[4][NE];
#pragma unroll
    for (int it = 0; it < 4; it++)
#pragma unroll
        for (int e = 0; e < NE; e++) acc[it][e] = 0.0;

#pragma unroll 1
    for (int h = 0; h < 2; h++) {
        __syncthreads();   // h=0: guard lcnt init; h=1: all reads of half0 done
        for (int i = threadIdx.x; i < 8192; i += 256) {
            int d = i >> 3, e = i & 7;
            wgs[e * 1024 + d] = Wg[(size_t)(h * 1024 + d) * 8 + e];
        }
        __syncthreads();
#pragma unroll 1
        for (int i = 0; i < 4; i++) {
            int dl = i * 256 + l * 4;          // local d within half
            int d0 = h * 1024 + dl;
            float4 xv[4];
#pragma unroll
            for (int it = 0; it < 4; it++) {
                xv[it] = *(const float4*)(x + (size_t)(tbase + it) * DIM + d0);
                half4v hv;
                hv[0] = (_Float16)xv[it].x; hv[1] = (_Float16)xv[it].y;
                hv[2] = (_Float16)xv[it].z; hv[3] = (_Float16)xv[it].w;
                *(half4v*)(xh + (size_t)(tbase + it) * DIM + d0) = hv;
            }
#pragma unroll
            for (int e = 0; e < NE; e++) {
                float4 w4 = *(const float4*)(wgs + e * 1024 + dl);
#pragma unroll
                for (int it = 0; it < 4; it++) {
                    acc[it][e] += (double)xv[it].x * w4.x + (double)xv[it].y * w4.y +
                                  (double)xv[it].z * w4.z + (double)xv[it].w * w4.w;
                }
            }
        }
    }

#pragma unroll 1
    for (int it = 0; it < 4; it++) {
        int t = tbase + it;
#pragma unroll
        for (int e = 0; e < NE; e++) {
            double v = acc[it][e];
            v += __shfl_xor(v, 32, 64); v += __shfl_xor(v, 16, 64);
            v += __shfl_xor(v, 8, 64);  v += __shfl_xor(v, 4, 64);
            v += __shfl_xor(v, 2, 64);  v += __shfl_xor(v, 1, 64);
            acc[it][e] = v;
        }
        if (l == 0) {
            double best0 = -1e300, best1 = -1e300; int i0 = 0, i1 = 0;
#pragma unroll
            for (int e = 0; e < NE; e++) {
                double lg = acc[it][e] + (double)bg[e];
                if (lg > best0) { best1 = best0; i1 = i0; best0 = lg; i0 = e; }
                else if (lg > best1) { best1 = lg; i1 = e; }
            }
            float d  = expf((float)(best1 - best0));
            float w0 = 1.f / (1.f + d), w1 = d / (1.f + d);
            te[2 * t] = i0; te[2 * t + 1] = i1;
            tw[2 * t] = w0; tw[2 * t + 1] = w1;
            atomicAdd(&lcnt[i0], 1);
            atomicAdd(&lcnt[i1], 1);
        }
    }
    __syncthreads();
    if (threadIdx.x < NE) atomicAdd(&counts[threadIdx.x], lcnt[threadIdx.x]);
}

// ---------------- route: scan (128-padded arena offsets + job table) + scatter ----------------
__global__ __launch_bounds__(256) void k_route(const int* __restrict__ counts,
                                               int* __restrict__ poff, int* __restrict__ cj,
                                               const int* __restrict__ te,
                                               const float* __restrict__ tw,
                                               int* __restrict__ ltok, float* __restrict__ lw,
                                               int* __restrict__ tslot) {
    __shared__ int spoff[NE], sfill[NE];
    if (threadIdx.x == 0) {
        int a = 0, jc = 0;
        for (int e = 0; e < NE; e++) {
            poff[e] = a; cj[e] = jc; spoff[e] = a;
            int mb = (counts[e] + 127) >> 7;
            a  += mb << 7;
            jc += mb * 16;       // 16 n-tiles of 128
        }
        poff[NE] = a; cj[NE] = jc;
    }
    if (threadIdx.x < NE) sfill[threadIdx.x] = 0;
    __syncthreads();
#pragma unroll 1
    for (int t = threadIdx.x; t < N_TOK; t += 256) {
#pragma unroll
        for (int k = 0; k < 2; k++) {
            int e = te[2 * t + k];
            int p = atomicAdd(&sfill[e], 1);
            int idx = spoff[e] + p;
            ltok[idx] = t; lw[idx] = tw[2 * t + k]; tslot[2 * t + k] = idx;
        }
    }
}

// ====== m97-style GEMM: BM=BN=128, BK=64, single-buffer, 4 blocks/CU ======
// 256 thr = 4 waves (2m x 2n); wave tile 64x64; acc[4][4] of 16x16x32_f16.
// LDS 32 KB single buffer; __launch_bounds__(256,4): 4 blocks/CU resident.
// Co-resident blocks fill each other's drain/barrier stalls (m114; m97's
// proven geometry -> MfmaUtil ~38%, the documented plateau of this structure).
// Proven-kept: arena padding (no row guards), nb-inner job order, XOR swizzle
// both-sides (rule 21), W2 transpose riding in the gemm1 dispatch tail.

template<int LAYER>
__global__ __launch_bounds__(256, 4) void k_gemm(const _Float16* __restrict__ Ain,
                                                 const _Float16* __restrict__ Bt,
                                                 const float* __restrict__ bias,
                                                 const int* __restrict__ cj,
                                                 const int* __restrict__ poff,
                                                 const int* __restrict__ ltok,
                                                 const float* __restrict__ lw,
                                                 const float* __restrict__ W2in,
                                                 _Float16* __restrict__ w2tO,
                                                 _Float16* __restrict__ Cout) {
    __shared__ __align__(16) char smem[32768];
    int j = blockIdx.x;

    if constexpr (LAYER == 1) {
        if (j >= NJOBS) {
            // ---------------- W2 transpose (256 threads) ----------------
            float (*tile)[65] = (float (*)[65])smem;      // 16.6 KB of the 32
            int b2 = j - NJOBS;
            int e = b2 >> 10, rem = b2 & 1023;
            int r0 = (rem >> 5) * 64, c0 = (rem & 31) * 64;
            int tc = threadIdx.x & 63, tr = threadIdx.x >> 6;   // tr 0..3
            const float* ip = W2in + ((size_t)e * 2048 + r0) * 2048 + c0;
#pragma unroll
            for (int i = 0; i < 16; i++)
                tile[tr + i * 4][tc] = ip[(size_t)(tr + i * 4) * 2048 + tc];
            __syncthreads();
            _Float16* op = w2tO + ((size_t)e * 2048 + c0) * 2048 + r0;
#pragma unroll
            for (int i = 0; i < 16; i++) {
                int cc = tr + i * 4;
                op[(size_t)cc * 2048 + tc] = (_Float16)tile[tc][cc];
            }
            return;
        }
    }

    _Float16* As = (_Float16*)smem;             // 128x64 halves = 16 KB
    _Float16* Bs = (_Float16*)(smem + 16384);   // 128x64 halves = 16 KB

    if (j >= cj[NE]) return;
    int e = 0;
#pragma unroll
    for (int k = 0; k < NE - 1; k++) e += (j >= cj[k + 1]);
    int r  = j - cj[e];
    int m0 = poff[e] + (r >> 4) * 128;   // arena row base
    int n0 = (r & 15) * 128;

    int tid = threadIdx.x;
    int l = tid & 63;
    int wid = tid >> 6;
    int wm = wid >> 1, wn = wid & 1;     // 2m x 2n
    int lr = l & 15, lk = l >> 4;
    int rA = (wm * 64 + lr) * 64;
    int rB = (wn * 64 + lr) * 64;

    int sd = tid * 8;                    // staging dest (lane-linear, m104-safe)
    size_t koff = (size_t)(((tid & 7) ^ ((tid >> 3) & 7)) * 8);  // pre-swizzled

    // each round of 256 thr covers 32 rows (tid>>3) x 8 chunks (tid&7)
    const _Float16* aS[4];
#pragma unroll
    for (int q = 0; q < 4; q++) {
        int ar = m0 + (tid >> 3) + q * 32;
        if constexpr (LAYER == 1) {
            int tok = ltok[ar];
            aS[q] = Ain + (size_t)tok * DIM + koff;
        } else {
            aS[q] = Ain + (size_t)ar * HID + koff;
        }
    }
    const _Float16* bS[4];
#pragma unroll
    for (int q = 0; q < 4; q++)
        bS[q] = Bt + ((size_t)(e * 2048 + n0 + (tid >> 3) + q * 32)) * 2048 + koff;

    floatx4 acc[4][4];
#pragma unroll
    for (int m = 0; m < 4; m++)
#pragma unroll
        for (int n = 0; n < 4; n++) acc[m][n] = (floatx4){0.f, 0.f, 0.f, 0.f};

    // prologue: stage tile 0 (4 A + 4 B rounds of 2048 halves)
#pragma unroll
    for (int q = 0; q < 4; q++) gload_lds16(aS[q], As + sd + q * 2048);
#pragma unroll
    for (int q = 0; q < 4; q++) gload_lds16(bS[q], Bs + sd + q * 2048);

#pragma unroll 1
    for (int t = 0; t < 32; ++t) {
        VMC0;    // staged tile t landed (co-resident blocks cover this drain)
        BARR;
#pragma unroll
        for (int kk = 0; kk < 2; kk++) {
            int cbo = ((kk * 4 + lk) ^ (lr & 7)) * 8;
            half8 a[4], b[4];
#pragma unroll
            for (int fm = 0; fm < 4; fm++)
                a[fm] = *(const half8*)(As + rA + fm * 1024 + cbo);
#pragma unroll
            for (int fn = 0; fn < 4; fn++)
                b[fn] = *(const half8*)(Bs + rB + fn * 1024 + cbo);
#pragma unroll
            for (int fn = 0; fn < 4; fn++)
#pragma unroll
                for (int fm = 0; fm < 4; fm++)
                    acc[fm][fn] = MF(a[fm], b[fn], acc[fm][fn]);
        }
        LGKM0;   // own reads retired
        BARR;    // all waves done reading -> safe to overwrite buffer
        if (t < 31) {
#pragma unroll
            for (int q = 0; q < 4; q++)
                gload_lds16(aS[q] + (size_t)(t + 1) * 64, As + sd + q * 2048);
#pragma unroll
            for (int q = 0; q < 4; q++)
                gload_lds16(bS[q] + (size_t)(t + 1) * 64, Bs + sd + q * 2048);
        }
    }

    // epilogue (no row guards - arena is padded)
#pragma unroll
    for (int fm = 0; fm < 4; fm++) {
        int row0 = m0 + wm * 64 + fm * 16 + lk * 4;
#pragma unroll
        for (int fn = 0; fn < 4; fn++) {
            int col = n0 + wn * 64 + fn * 16 + lr;
            float bv = bias[e * 2048 + col];
#pragma unroll
            for (int rr = 0; rr < 4; rr++) {
                int row = row0 + rr;
                float v = acc[fm][fn][rr] + bv;
                if constexpr (LAYER == 1) {
                    v = v > 0.f ? v : 0.f;
                } else {
                    v *= lw[row];
                }
                Cout[(size_t)row * HID + col] = (_Float16)v;
            }
        }
    }
}

// ---------------- combine the two weighted expert rows per token ----------------
__global__ __launch_bounds__(256) void k_combine(const _Float16* __restrict__ yb,
                                                 const int* __restrict__ tslot,
                                                 float* __restrict__ out) {
    int t = blockIdx.x;
    int s0 = tslot[2 * t], s1 = tslot[2 * t + 1];
    int c = threadIdx.x * 8;
    half8 y0 = *(const half8*)&yb[(size_t)s0 * HID + c];
    half8 y1 = *(const half8*)&yb[(size_t)s1 * HID + c];
    float* op = out + (size_t)t * HID + c;
    float4 o;
    o.x = (float)y0[0] + (float)y1[0];
    o.y = (float)y0[1] + (float)y1[1];
    o.z = (float)y0[2] + (float)y1[2];
    o.w = (float)y0[3] + (float)y1[3];
    *(float4*)(op) = o;
    o.x = (float)y0[4] + (float)y1[4];
    o.y = (float)y0[5] + (float)y1[5];
    o.z = (float)y0[6] + (float)y1[6];
    o.w = (float)y0[7] + (float)y1[7];
    *(float4*)(op + 4) = o;
}

extern "C" void kernel_launch(void* const* d_in, const int* in_sizes, int n_in,
                              void* d_out, int out_size, void* d_ws, size_t ws_size,
                              hipStream_t stream) {
    const float* x  = (const float*)d_in[0];
    const float* Wg = (const float*)d_in[1];
    const float* bg = (const float*)d_in[2];
    const float* W1 = (const float*)d_in[3];
    const float* b1 = (const float*)d_in[4];
    const float* W2 = (const float*)d_in[5];
    const float* b2 = (const float*)d_in[6];
    float* out = (float*)d_out;

    // ws layout (yb aliases xh+w1t, both dead by gemm2)
    char* ws = (char*)d_ws;
    _Float16* xh  = (_Float16*)(ws);
    _Float16* yb  = (_Float16*)(ws);                        // alias: safe, see order
    _Float16* w1t = (_Float16*)(ws + 33554432ULL);
    _Float16* w2t = (_Float16*)(ws + 100663296ULL);
    _Float16* hb  = (_Float16*)(ws + 167772160ULL);
    char* rt = ws + 167772160ULL + (size_t)ARENA * HID * 2; // 243,269,632
    int*   counts = (int*)(rt);              // 8
    int*   poff   = (int*)(rt + 64);         // 9
    int*   cj     = (int*)(rt + 128);        // 9
    int*   te     = (int*)(rt + 192);        // 16384 ints
    float* tw     = (float*)(rt + 192 + 65536);
    int*   tslot  = (int*)(rt + 192 + 131072);
    int*   ltok   = (int*)(rt + 192 + 196608);              // ARENA ints
    float* lw     = (float*)(rt + 192 + 196608 + 73728);    // ARENA floats

    hipMemsetAsync(rt, 0, 64, stream);                   // counts
    hipMemsetAsync(ltok, 0, (size_t)ARENA * 8, stream);  // ltok + lw pads = 0
    k_prep_gate<<<dim3(8704), 256, 0, stream>>>(W1, w1t, x, Wg, bg, xh, te, tw, counts);
    k_route<<<1, 256, 0, stream>>>(counts, poff, cj, te, tw, ltok, lw, tslot);
    k_gemm<1><<<dim3(NJOBS + 8192), 256, 0, stream>>>(xh, w1t, b1, cj, poff, ltok,
                                                      nullptr, W2, w2t, hb);
    k_gemm<2><<<dim3(NJOBS), 256, 0, stream>>>(hb, w2t, b2, cj, poff, ltok, lw,
                                               nullptr, nullptr, yb);
    k_combine<<<8192, 256, 0, stream>>>(yb, tslot, out);
}

// Round 20
// 581.691 us; speedup vs baseline: 1.0020x; 1.0020x over previous
//
#include <hip/hip_runtime.h>
#include <hip/hip_bf16.h>
#include <cstdint>
#include <cstddef>

#define N_TOK 8192
#define DIM   2048
#define HID   2048
#define NE    8
#define ARENA 18432   // >= 16384 + 8*127 padded rows (pad granularity 128)
#define NJOBS 2176    // >= sum_e ceil(cnt_e/128)*16  (<= 136*16)

typedef _Float16 half8  __attribute__((ext_vector_type(8)));
typedef _Float16 half4v __attribute__((ext_vector_type(4)));
typedef float    floatx4 __attribute__((ext_vector_type(4)));

#define BARR  __builtin_amdgcn_s_barrier()
#define LGKM0 asm volatile("s_waitcnt lgkmcnt(0)" ::: "memory")
#define VMC0  asm volatile("s_waitcnt vmcnt(0)" ::: "memory")

__device__ inline void gload_lds16(const void* g, void* l) {
    __builtin_amdgcn_global_load_lds(
        (const __attribute__((address_space(1))) unsigned int*)g,
        (__attribute__((address_space(3))) unsigned int*)l, 16, 0, 0);
}

__device__ __forceinline__ floatx4 MF(half8 a, half8 b, floatx4 c) {
    return __builtin_amdgcn_mfma_f32_16x16x32_f16(a, b, c, 0, 0, 0);
}

// ========== merged gate (two-pass 32KB LDS) + prep(W1 transpose->fp16) ==========
// blocks [0,512): gate — Wg staged in TWO 1024-dim halves (32 KB wgs) so the
//   merged kernel's static LDS is 32.8 KB, not 65.6 KB.  Per-token fp64
//   accumulation order is d-ascending in the same 4-dim groups as R13-R17 ->
//   bit-identical logits -> identical routing.  (R18's register gate lost to
//   uncoalesced 128B-stride Wg reads; R17's 64KB gate LDS capped prep at 2/CU.)
// blocks [512,8704): transpose W1 [E][R][C] fp32 -> [E][C][R] fp16 — now 4
//   blocks/CU resident (32.8 KB < 40 KB) -> full-rate HBM streaming.
__global__ __launch_bounds__(256, 4) void k_prep_gate(
        const float* __restrict__ W1, _Float16* __restrict__ w1t,
        const float* __restrict__ x, const float* __restrict__ Wg,
        const float* __restrict__ bg, _Float16* __restrict__ xh,
        int* __restrict__ te, float* __restrict__ tw, int* __restrict__ counts) {
    __shared__ __align__(16) char smem[32800];
    int b = blockIdx.x;
    if (b >= 512) {
        // ---------------- prep W1 ----------------
        float (*tile)[65] = (float (*)[65])smem;   // 16.6 KB of the 32.8
        int bb = b - 512;
        int e = bb >> 10, rem = bb & 1023;
        int r0 = (rem >> 5) * 64, c0 = (rem & 31) * 64;
        int tc = threadIdx.x & 63, tr = threadIdx.x >> 6;   // tr 0..3
        const float* ip = W1 + ((size_t)e * 2048 + r0) * 2048 + c0;
#pragma unroll
        for (int i = 0; i < 16; i++)
            tile[tr + i * 4][tc] = ip[(size_t)(tr + i * 4) * 2048 + tc];
        __syncthreads();
        _Float16* op = w1t + ((size_t)e * 2048 + c0) * 2048 + r0;
#pragma unroll
        for (int i = 0; i < 16; i++) {
            int cc = tr + i * 4;
            op[(size_t)cc * 2048 + tc] = (_Float16)tile[tc][cc];
        }
        return;
    }
    // ---------------- gate (two-pass over d halves) ----------------
    float* wgs = (float*)smem;              // [8][1024] for current half
    int* lcnt  = (int*)(smem + 32768);
    if (threadIdx.x < NE) lcnt[threadIdx.x] = 0;
    int wv = threadIdx.x >> 6, l = threadIdx.x & 63;
    int tbase = b * 16 + wv * 4;
    double acc[4][NE];
#pragma unroll
    for (int it = 0; it < 4; it++)
#pragma unroll
        for (int e = 0; e < NE; e++) acc[it][e] = 0.0;

#pragma unroll 1
    for (int h = 0; h < 2; h++) {
        __syncthreads();   // h=0: guard lcnt init; h=1: all reads of half0 done
        for (int i = threadIdx.x; i < 8192; i += 256) {
            int d = i >> 3, e = i & 7;
            wgs[e * 1024 + d] = Wg[(size_t)(h * 1024 + d) * 8 + e];
        }
        __syncthreads();
#pragma unroll 1
        for (int i = 0; i < 4; i++) {
            int dl = i * 256 + l * 4;          // local d within half
            int d0 = h * 1024 + dl;
            float4 xv[4];
#pragma unroll
            for (int it = 0; it < 4; it++) {
                xv[it] = *(const float4*)(x + (size_t)(tbase + it) * DIM + d0);
                half4v hv;
                hv[0] = (_Float16)xv[it].x; hv[1] = (_Float16)xv[it].y;
                hv[2] = (_Float16)xv[it].z; hv[3] = (_Float16)xv[it].w;
                *(half4v*)(xh + (size_t)(tbase + it) * DIM + d0) = hv;
            }
#pragma unroll
            for (int e = 0; e < NE; e++) {
                float4 w4 = *(const float4*)(wgs + e * 1024 + dl);
#pragma unroll
                for (int it = 0; it < 4; it++) {
                    acc[it][e] += (double)xv[it].x * w4.x + (double)xv[it].y * w4.y +
                                  (double)xv[it].z * w4.z + (double)xv[it].w * w4.w;
                }
            }
        }
    }

#pragma unroll 1
    for (int it = 0; it < 4; it++) {
        int t = tbase + it;
#pragma unroll
        for (int e = 0; e < NE; e++) {
            double v = acc[it][e];
            v += __shfl_xor(v, 32, 64); v += __shfl_xor(v, 16, 64);
            v += __shfl_xor(v, 8, 64);  v += __shfl_xor(v, 4, 64);
            v += __shfl_xor(v, 2, 64);  v += __shfl_xor(v, 1, 64);
            acc[it][e] = v;
        }
        if (l == 0) {
            double best0 = -1e300, best1 = -1e300; int i0 = 0, i1 = 0;
#pragma unroll
            for (int e = 0; e < NE; e++) {
                double lg = acc[it][e] + (double)bg[e];
                if (lg > best0) { best1 = best0; i1 = i0; best0 = lg; i0 = e; }
                else if (lg > best1) { best1 = lg; i1 = e; }
            }
            float d  = expf((float)(best1 - best0));
            float w0 = 1.f / (1.f + d), w1 = d / (1.f + d);
            te[2 * t] = i0; te[2 * t + 1] = i1;
            tw[2 * t] = w0; tw[2 * t + 1] = w1;
            atomicAdd(&lcnt[i0], 1);
            atomicAdd(&lcnt[i1], 1);
        }
    }
    __syncthreads();
    if (threadIdx.x < NE) atomicAdd(&counts[threadIdx.x], lcnt[threadIdx.x]);
}

// ---------------- route: scan (128-padded arena offsets + job table) + scatter ----------------
__global__ __launch_bounds__(256) void k_route(const int* __restrict__ counts,
                                               int* __restrict__ poff, int* __restrict__ cj,
                                               const int* __restrict__ te,
                                               const float* __restrict__ tw,
                                               int* __restrict__ ltok, float* __restrict__ lw,
                                               int* __restrict__ tslot) {
    __shared__ int spoff[NE], sfill[NE];
    if (threadIdx.x == 0) {
        int a = 0, jc = 0;
        for (int e = 0; e < NE; e++) {
            poff[e] = a; cj[e] = jc; spoff[e] = a;
            int mb = (counts[e] + 127) >> 7;
            a  += mb << 7;
            jc += mb * 16;       // 16 n-tiles of 128
        }
        poff[NE] = a; cj[NE] = jc;
    }
    if (threadIdx.x < NE) sfill[threadIdx.x] = 0;
    __syncthreads();
#pragma unroll 1
    for (int t = threadIdx.x; t < N_TOK; t += 256) {
#pragma unroll
        for (int k = 0; k < 2; k++) {
            int e = te[2 * t + k];
            int p = atomicAdd(&sfill[e], 1);
            int idx = spoff[e] + p;
            ltok[idx] = t; lw[idx] = tw[2 * t + k]; tslot[2 * t + k] = idx;
        }
    }
}

// ====== m97-style GEMM: BM=BN=128, BK=64, single-buffer, 4 blocks/CU ======
// 256 thr = 4 waves (2m x 2n); wave tile 64x64; acc[4][4] of 16x16x32_f16.
// LDS 32 KB single buffer; __launch_bounds__(256,4): 4 blocks/CU resident.
// Co-resident blocks fill each other's drain/barrier stalls (m114; m97's
// proven geometry -> MfmaUtil ~38%, the documented plateau of this structure).
// Proven-kept: arena padding (no row guards), nb-inner job order, XOR swizzle
// both-sides (rule 21), W2 transpose riding in the gemm1 dispatch tail.

template<int LAYER>
__global__ __launch_bounds__(256, 4) void k_gemm(const _Float16* __restrict__ Ain,
                                                 const _Float16* __restrict__ Bt,
                                                 const float* __restrict__ bias,
                                                 const int* __restrict__ cj,
                                                 const int* __restrict__ poff,
                                                 const int* __restrict__ ltok,
                                                 const float* __restrict__ lw,
                                                 const float* __restrict__ W2in,
                                                 _Float16* __restrict__ w2tO,
                                                 _Float16* __restrict__ Cout) {
    __shared__ __align__(16) char smem[32768];
    int j = blockIdx.x;

    if constexpr (LAYER == 1) {
        if (j >= NJOBS) {
            // ---------------- W2 transpose (256 threads) ----------------
            float (*tile)[65] = (float (*)[65])smem;      // 16.6 KB of the 32
            int b2 = j - NJOBS;
            int e = b2 >> 10, rem = b2 & 1023;
            int r0 = (rem >> 5) * 64, c0 = (rem & 31) * 64;
            int tc = threadIdx.x & 63, tr = threadIdx.x >> 6;   // tr 0..3
            const float* ip = W2in + ((size_t)e * 2048 + r0) * 2048 + c0;
#pragma unroll
            for (int i = 0; i < 16; i++)
                tile[tr + i * 4][tc] = ip[(size_t)(tr + i * 4) * 2048 + tc];
            __syncthreads();
            _Float16* op = w2tO + ((size_t)e * 2048 + c0) * 2048 + r0;
#pragma unroll
            for (int i = 0; i < 16; i++) {
                int cc = tr + i * 4;
                op[(size_t)cc * 2048 + tc] = (_Float16)tile[tc][cc];
            }
            return;
        }
    }

    _Float16* As = (_Float16*)smem;             // 128x64 halves = 16 KB
    _Float16* Bs = (_Float16*)(smem + 16384);   // 128x64 halves = 16 KB

    if (j >= cj[NE]) return;
    int e = 0;
#pragma unroll
    for (int k = 0; k < NE - 1; k++) e += (j >= cj[k + 1]);
    int r  = j - cj[e];
    int m0 = poff[e] + (r >> 4) * 128;   // arena row base
    int n0 = (r & 15) * 128;

    int tid = threadIdx.x;
    int l = tid & 63;
    int wid = tid >> 6;
    int wm = wid >> 1, wn = wid & 1;     // 2m x 2n
    int lr = l & 15, lk = l >> 4;
    int rA = (wm * 64 + lr) * 64;
    int rB = (wn * 64 + lr) * 64;

    int sd = tid * 8;                    // staging dest (lane-linear, m104-safe)
    size_t koff = (size_t)(((tid & 7) ^ ((tid >> 3) & 7)) * 8);  // pre-swizzled

    // each round of 256 thr covers 32 rows (tid>>3) x 8 chunks (tid&7)
    const _Float16* aS[4];
#pragma unroll
    for (int q = 0; q < 4; q++) {
        int ar = m0 + (tid >> 3) + q * 32;
        if constexpr (LAYER == 1) {
            int tok = ltok[ar];
            aS[q] = Ain + (size_t)tok * DIM + koff;
        } else {
            aS[q] = Ain + (size_t)ar * HID + koff;
        }
    }
    const _Float16* bS[4];
#pragma unroll
    for (int q = 0; q < 4; q++)
        bS[q] = Bt + ((size_t)(e * 2048 + n0 + (tid >> 3) + q * 32)) * 2048 + koff;

    floatx4 acc[4][4];
#pragma unroll
    for (int m = 0; m < 4; m++)
#pragma unroll
        for (int n = 0; n < 4; n++) acc[m][n] = (floatx4){0.f, 0.f, 0.f, 0.f};

    // prologue: stage tile 0 (4 A + 4 B rounds of 2048 halves)
#pragma unroll
    for (int q = 0; q < 4; q++) gload_lds16(aS[q], As + sd + q * 2048);
#pragma unroll
    for (int q = 0; q < 4; q++) gload_lds16(bS[q], Bs + sd + q * 2048);

#pragma unroll 1
    for (int t = 0; t < 32; ++t) {
        VMC0;    // staged tile t landed (co-resident blocks cover this drain)
        BARR;
#pragma unroll
        for (int kk = 0; kk < 2; kk++) {
            int cbo = ((kk * 4 + lk) ^ (lr & 7)) * 8;
            half8 a[4], b[4];
#pragma unroll
            for (int fm = 0; fm < 4; fm++)
                a[fm] = *(const half8*)(As + rA + fm * 1024 + cbo);
#pragma unroll
            for (int fn = 0; fn < 4; fn++)
                b[fn] = *(const half8*)(Bs + rB + fn * 1024 + cbo);
#pragma unroll
            for (int fn = 0; fn < 4; fn++)
#pragma unroll
                for (int fm = 0; fm < 4; fm++)
                    acc[fm][fn] = MF(a[fm], b[fn], acc[fm][fn]);
        }
        LGKM0;   // own reads retired
        BARR;    // all waves done reading -> safe to overwrite buffer
        if (t < 31) {
#pragma unroll
            for (int q = 0; q < 4; q++)
                gload_lds16(aS[q] + (size_t)(t + 1) * 64, As + sd + q * 2048);
#pragma unroll
            for (int q = 0; q < 4; q++)
                gload_lds16(bS[q] + (size_t)(t + 1) * 64, Bs + sd + q * 2048);
        }
    }

    // epilogue (no row guards - arena is padded)
#pragma unroll
    for (int fm = 0; fm < 4; fm++) {
        int row0 = m0 + wm * 64 + fm * 16 + lk * 4;
#pragma unroll
        for (int fn = 0; fn < 4; fn++) {
            int col = n0 + wn * 64 + fn * 16 + lr;
            float bv = bias[e * 2048 + col];
#pragma unroll
            for (int rr = 0; rr < 4; rr++) {
                int row = row0 + rr;
                float v = acc[fm][fn][rr] + bv;
                if constexpr (LAYER == 1) {
                    v = v > 0.f ? v : 0.f;
                } else {
                    v *= lw[row];
                }
                Cout[(size_t)row * HID + col] = (_Float16)v;
            }
        }
    }
}

// ---------------- combine the two weighted expert rows per token ----------------
__global__ __launch_bounds__(256) void k_combine(const _Float16* __restrict__ yb,
                                                 const int* __restrict__ tslot,
                                                 float* __restrict__ out) {
    int t = blockIdx.x;
    int s0 = tslot[2 * t], s1 = tslot[2 * t + 1];
    int c = threadIdx.x * 8;
    half8 y0 = *(const half8*)&yb[(size_t)s0 * HID + c];
    half8 y1 = *(const half8*)&yb[(size_t)s1 * HID + c];
    float* op = out + (size_t)t * HID + c;
    float4 o;
    o.x = (float)y0[0] + (float)y1[0];
    o.y = (float)y0[1] + (float)y1[1];
    o.z = (float)y0[2] + (float)y1[2];
    o.w = (float)y0[3] + (float)y1[3];
    *(float4*)(op) = o;
    o.x = (float)y0[4] + (float)y1[4];
    o.y = (float)y0[5] + (float)y1[5];
    o.z = (float)y0[6] + (float)y1[6];
    o.w = (float)y0[7] + (float)y1[7];
    *(float4*)(op + 4) = o;
}

extern "C" void kernel_launch(void* const* d_in, const int* in_sizes, int n_in,
                              void* d_out, int out_size, void* d_ws, size_t ws_size,
                              hipStream_t stream) {
    const float* x  = (const float*)d_in[0];
    const float* Wg = (const float*)d_in[1];
    const float* bg = (const float*)d_in[2];
    const float* W1 = (const float*)d_in[3];
    const float* b1 = (const float*)d_in[4];
    const float* W2 = (const float*)d_in[5];
    const float* b2 = (const float*)d_in[6];
    float* out = (float*)d_out;

    // ws layout (yb aliases xh+w1t, both dead by gemm2)
    char* ws = (char*)d_ws;
    _Float16* xh  = (_Float16*)(ws);
    _Float16* yb  = (_Float16*)(ws);                        // alias: safe, see order
    _Float16* w1t = (_Float16*)(ws + 33554432ULL);
    _Float16* w2t = (_Float16*)(ws + 100663296ULL);
    _Float16* hb  = (_Float16*)(ws + 167772160ULL);
    char* rt = ws + 167772160ULL + (size_t)ARENA * HID * 2; // 243,269,632
    int*   counts = (int*)(rt);              // 8
    int*   poff   = (int*)(rt + 64);         // 9
    int*   cj     = (int*)(rt + 128);        // 9
    int*   te     = (int*)(rt + 192);        // 16384 ints
    float* tw     = (float*)(rt + 192 + 65536);
    int*   tslot  = (int*)(rt + 192 + 131072);
    int*   ltok   = (int*)(rt + 192 + 196608);              // ARENA ints
    float* lw     = (float*)(rt + 192 + 196608 + 73728);    // ARENA floats

    hipMemsetAsync(rt, 0, 64, stream);                   // counts
    hipMemsetAsync(ltok, 0, (size_t)ARENA * 8, stream);  // ltok + lw pads = 0
    k_prep_gate<<<dim3(8704), 256, 0, stream>>>(W1, w1t, x, Wg, bg, xh, te, tw, counts);
    k_route<<<1, 256, 0, stream>>>(counts, poff, cj, te, tw, ltok, lw, tslot);
    k_gemm<1><<<dim3(NJOBS + 8192), 256, 0, stream>>>(xh, w1t, b1, cj, poff, ltok,
                                                      nullptr, W2, w2t, hb);
    k_gemm<2><<<dim3(NJOBS), 256, 0, stream>>>(hb, w2t, b2, cj, poff, ltok, lw,
                                               nullptr, nullptr, yb);
    k_combine<<<8192, 256, 0, stream>>>(yb, tslot, out);
}

// Round 21
// 431.713 us; speedup vs baseline: 1.3501x; 1.3474x over previous
//
#include <hip/hip_runtime.h>
#include <hip/hip_bf16.h>
#include <cstdint>
#include <cstddef>

#define N_TOK 8192
#define DIM   2048
#define HID   2048
#define NE    8
#define ARENA 18432   // >= 16384 + 8*127 padded rows (pad granularity 128)
#define NJOBS 2176    // >= sum_e ceil(cnt_e/128)*16  (<= 136*16)

typedef _Float16 half8  __attribute__((ext_vector_type(8)));
typedef _Float16 half4v __attribute__((ext_vector_type(4)));
typedef float    floatx4 __attribute__((ext_vector_type(4)));

#define BARR  __builtin_amdgcn_s_barrier()
#define LGKM0 asm volatile("s_waitcnt lgkmcnt(0)" ::: "memory")
#define VMC0  asm volatile("s_waitcnt vmcnt(0)" ::: "memory")

__device__ inline void gload_lds16(const void* g, void* l) {
    __builtin_amdgcn_global_load_lds(
        (const __attribute__((address_space(1))) unsigned int*)g,
        (__attribute__((address_space(3))) unsigned int*)l, 16, 0, 0);
}

__device__ __forceinline__ floatx4 MF(half8 a, half8 b, floatx4 c) {
    return __builtin_amdgcn_mfma_f32_16x16x32_f16(a, b, c, 0, 0, 0);
}

// ========== merged gate (logits/top2/x->fp16) + prep(W1 transpose->fp16) ==========
// blocks [0,512): gate — scheduled FIRST so the latency-bound gate runs fully
//   under the HBM-bound W1 prep.  64KB LDS gate math (proven; register-gate
//   R18 and two-pass-gate R19/R20 both regressed).
// blocks [512,8704): transpose W1 [E][R][C] fp32 -> [E][C][R] fp16.
// (W2's transpose rides inside the gemm1 dispatch - it is not a gemm1 dep.)
__global__ __launch_bounds__(256) void k_prep_gate(
        const float* __restrict__ W1, _Float16* __restrict__ w1t,
        const float* __restrict__ x, const float* __restrict__ Wg,
        const float* __restrict__ bg, _Float16* __restrict__ xh,
        int* __restrict__ te, float* __restrict__ tw, int* __restrict__ counts) {
    __shared__ __align__(16) char smem[65568];
    int b = blockIdx.x;
    if (b >= 512) {
        // ---------------- prep W1 ----------------
        float (*tile)[65] = (float (*)[65])smem;
        int bb = b - 512;
        int e = bb >> 10, rem = bb & 1023;
        int r0 = (rem >> 5) * 64, c0 = (rem & 31) * 64;
        int tc = threadIdx.x & 63, tr = threadIdx.x >> 6;   // tr 0..3
        const float* ip = W1 + ((size_t)e * 2048 + r0) * 2048 + c0;
#pragma unroll
        for (int i = 0; i < 16; i++)
            tile[tr + i * 4][tc] = ip[(size_t)(tr + i * 4) * 2048 + tc];
        __syncthreads();
        _Float16* op = w1t + ((size_t)e * 2048 + c0) * 2048 + r0;
#pragma unroll
        for (int i = 0; i < 16; i++) {
            int cc = tr + i * 4;
            op[(size_t)cc * 2048 + tc] = (_Float16)tile[tc][cc];
        }
        return;
    }
    // ---------------- gate ----------------
    int bid = b;
    float* wgs = (float*)smem;             // 64 KB transposed [e][d]
    int* lcnt  = (int*)(smem + 65536);
    if (threadIdx.x < NE) lcnt[threadIdx.x] = 0;
    for (int i = threadIdx.x; i < NE * DIM; i += 256)
        wgs[(i & 7) * DIM + (i >> 3)] = Wg[i];
    __syncthreads();
    int wv = threadIdx.x >> 6, l = threadIdx.x & 63;
#pragma unroll 1
    for (int it = 0; it < 4; ++it) {
        int t = bid * 16 + wv * 4 + it;
        const float* xr = x + (size_t)t * DIM;
        double acc[NE] = {0, 0, 0, 0, 0, 0, 0, 0};
#pragma unroll 2
        for (int i = 0; i < 8; i++) {
            int d0 = i * 256 + l * 4;
            float4 xv = *(const float4*)(xr + d0);
            half4v hv;
            hv[0] = (_Float16)xv.x; hv[1] = (_Float16)xv.y;
            hv[2] = (_Float16)xv.z; hv[3] = (_Float16)xv.w;
            *(half4v*)(xh + (size_t)t * DIM + d0) = hv;
#pragma unroll
            for (int e = 0; e < NE; e++) {
                float4 w4 = *(const float4*)(wgs + e * DIM + d0);
                acc[e] += (double)xv.x * w4.x + (double)xv.y * w4.y +
                          (double)xv.z * w4.z + (double)xv.w * w4.w;
            }
        }
#pragma unroll
        for (int e = 0; e < NE; e++) {
            double v = acc[e];
            v += __shfl_xor(v, 32, 64); v += __shfl_xor(v, 16, 64);
            v += __shfl_xor(v, 8, 64);  v += __shfl_xor(v, 4, 64);
            v += __shfl_xor(v, 2, 64);  v += __shfl_xor(v, 1, 64);
            acc[e] = v;
        }
        if (l == 0) {
            double best0 = -1e300, best1 = -1e300; int i0 = 0, i1 = 0;
#pragma unroll
            for (int e = 0; e < NE; e++) {
                double lg = acc[e] + (double)bg[e];
                if (lg > best0) { best1 = best0; i1 = i0; best0 = lg; i0 = e; }
                else if (lg > best1) { best1 = lg; i1 = e; }
            }
            float d  = expf((float)(best1 - best0));
            float w0 = 1.f / (1.f + d), w1 = d / (1.f + d);
            te[2 * t] = i0; te[2 * t + 1] = i1;
            tw[2 * t] = w0; tw[2 * t + 1] = w1;
            atomicAdd(&lcnt[i0], 1);
            atomicAdd(&lcnt[i1], 1);
        }
    }
    __syncthreads();
    if (threadIdx.x < NE) atomicAdd(&counts[threadIdx.x], lcnt[threadIdx.x]);
}

// ---------------- route: scan (128-padded arena offsets + job table) + scatter ----------------
__global__ __launch_bounds__(256) void k_route(const int* __restrict__ counts,
                                               int* __restrict__ poff, int* __restrict__ cj,
                                               const int* __restrict__ te,
                                               const float* __restrict__ tw,
                                               int* __restrict__ ltok, float* __restrict__ lw,
                                               int* __restrict__ tslot) {
    __shared__ int spoff[NE], sfill[NE];
    if (threadIdx.x == 0) {
        int a = 0, jc = 0;
        for (int e = 0; e < NE; e++) {
            poff[e] = a; cj[e] = jc; spoff[e] = a;
            int mb = (counts[e] + 127) >> 7;
            a  += mb << 7;
            jc += mb * 16;       // 16 n-tiles of 128
        }
        poff[NE] = a; cj[NE] = jc;
    }
    if (threadIdx.x < NE) sfill[threadIdx.x] = 0;
    __syncthreads();
#pragma unroll 1
    for (int t = threadIdx.x; t < N_TOK; t += 256) {
#pragma unroll
        for (int k = 0; k < 2; k++) {
            int e = te[2 * t + k];
            int p = atomicAdd(&sfill[e], 1);
            int idx = spoff[e] + p;
            ltok[idx] = t; lw[idx] = tw[2 * t + k]; tslot[2 * t + k] = idx;
        }
    }
}

// ====== m97-style GEMM: BM=BN=128, BK=64, single-buffer, 4 blocks/CU ======
// 256 thr = 4 waves (2m x 2n); wave tile 64x64; acc[4][4] of 16x16x32_f16.
// LDS 32 KB single buffer; __launch_bounds__(256,4): 4 blocks/CU resident.
// Co-resident blocks fill each other's drain/barrier stalls (m114; m97's
// proven geometry -> MfmaUtil ~38%, the documented plateau of this structure).
// Proven-kept: arena padding (no row guards), nb-inner job order, XOR swizzle
// both-sides (rule 21), W2 transpose riding in the gemm1 dispatch tail.

template<int LAYER>
__global__ __launch_bounds__(256, 4) void k_gemm(const _Float16* __restrict__ Ain,
                                                 const _Float16* __restrict__ Bt,
                                                 const float* __restrict__ bias,
                                                 const int* __restrict__ cj,
                                                 const int* __restrict__ poff,
                                                 const int* __restrict__ ltok,
                                                 const float* __restrict__ lw,
                                                 const float* __restrict__ W2in,
                                                 _Float16* __restrict__ w2tO,
                                                 _Float16* __restrict__ Cout) {
    __shared__ __align__(16) char smem[32768];
    int j = blockIdx.x;

    if constexpr (LAYER == 1) {
        if (j >= NJOBS) {
            // ---------------- W2 transpose (256 threads) ----------------
            float (*tile)[65] = (float (*)[65])smem;      // 16.6 KB of the 32
            int b2 = j - NJOBS;
            int e = b2 >> 10, rem = b2 & 1023;
            int r0 = (rem >> 5) * 64, c0 = (rem & 31) * 64;
            int tc = threadIdx.x & 63, tr = threadIdx.x >> 6;   // tr 0..3
            const float* ip = W2in + ((size_t)e * 2048 + r0) * 2048 + c0;
#pragma unroll
            for (int i = 0; i < 16; i++)
                tile[tr + i * 4][tc] = ip[(size_t)(tr + i * 4) * 2048 + tc];
            __syncthreads();
            _Float16* op = w2tO + ((size_t)e * 2048 + c0) * 2048 + r0;
#pragma unroll
            for (int i = 0; i < 16; i++) {
                int cc = tr + i * 4;
                op[(size_t)cc * 2048 + tc] = (_Float16)tile[tc][cc];
            }
            return;
        }
    }

    _Float16* As = (_Float16*)smem;             // 128x64 halves = 16 KB
    _Float16* Bs = (_Float16*)(smem + 16384);   // 128x64 halves = 16 KB

    if (j >= cj[NE]) return;
    int e = 0;
#pragma unroll
    for (int k = 0; k < NE - 1; k++) e += (j >= cj[k + 1]);
    int r  = j - cj[e];
    int m0 = poff[e] + (r >> 4) * 128;   // arena row base
    int n0 = (r & 15) * 128;

    int tid = threadIdx.x;
    int l = tid & 63;
    int wid = tid >> 6;
    int wm = wid >> 1, wn = wid & 1;     // 2m x 2n
    int lr = l & 15, lk = l >> 4;
    int rA = (wm * 64 + lr) * 64;
    int rB = (wn * 64 + lr) * 64;

    int sd = tid * 8;                    // staging dest (lane-linear, m104-safe)
    size_t koff = (size_t)(((tid & 7) ^ ((tid >> 3) & 7)) * 8);  // pre-swizzled

    // each round of 256 thr covers 32 rows (tid>>3) x 8 chunks (tid&7)
    const _Float16* aS[4];
#pragma unroll
    for (int q = 0; q < 4; q++) {
        int ar = m0 + (tid >> 3) + q * 32;
        if constexpr (LAYER == 1) {
            int tok = ltok[ar];
            aS[q] = Ain + (size_t)tok * DIM + koff;
        } else {
            aS[q] = Ain + (size_t)ar * HID + koff;
        }
    }
    const _Float16* bS[4];
#pragma unroll
    for (int q = 0; q < 4; q++)
        bS[q] = Bt + ((size_t)(e * 2048 + n0 + (tid >> 3) + q * 32)) * 2048 + koff;

    floatx4 acc[4][4];
#pragma unroll
    for (int m = 0; m < 4; m++)
#pragma unroll
        for (int n = 0; n < 4; n++) acc[m][n] = (floatx4){0.f, 0.f, 0.f, 0.f};

    // prologue: stage tile 0 (4 A + 4 B rounds of 2048 halves)
#pragma unroll
    for (int q = 0; q < 4; q++) gload_lds16(aS[q], As + sd + q * 2048);
#pragma unroll
    for (int q = 0; q < 4; q++) gload_lds16(bS[q], Bs + sd + q * 2048);

#pragma unroll 1
    for (int t = 0; t < 32; ++t) {
        VMC0;    // staged tile t landed (co-resident blocks cover this drain)
        BARR;
#pragma unroll
        for (int kk = 0; kk < 2; kk++) {
            int cbo = ((kk * 4 + lk) ^ (lr & 7)) * 8;
            half8 a[4], b[4];
#pragma unroll
            for (int fm = 0; fm < 4; fm++)
                a[fm] = *(const half8*)(As + rA + fm * 1024 + cbo);
#pragma unroll
            for (int fn = 0; fn < 4; fn++)
                b[fn] = *(const half8*)(Bs + rB + fn * 1024 + cbo);
#pragma unroll
            for (int fn = 0; fn < 4; fn++)
#pragma unroll
                for (int fm = 0; fm < 4; fm++)
                    acc[fm][fn] = MF(a[fm], b[fn], acc[fm][fn]);
        }
        LGKM0;   // own reads retired
        BARR;    // all waves done reading -> safe to overwrite buffer
        if (t < 31) {
#pragma unroll
            for (int q = 0; q < 4; q++)
                gload_lds16(aS[q] + (size_t)(t + 1) * 64, As + sd + q * 2048);
#pragma unroll
            for (int q = 0; q < 4; q++)
                gload_lds16(bS[q] + (size_t)(t + 1) * 64, Bs + sd + q * 2048);
        }
    }

    // epilogue (no row guards - arena is padded)
#pragma unroll
    for (int fm = 0; fm < 4; fm++) {
        int row0 = m0 + wm * 64 + fm * 16 + lk * 4;
#pragma unroll
        for (int fn = 0; fn < 4; fn++) {
            int col = n0 + wn * 64 + fn * 16 + lr;
            float bv = bias[e * 2048 + col];
#pragma unroll
            for (int rr = 0; rr < 4; rr++) {
                int row = row0 + rr;
                float v = acc[fm][fn][rr] + bv;
                if constexpr (LAYER == 1) {
                    v = v > 0.f ? v : 0.f;
                } else {
                    v *= lw[row];
                }
                Cout[(size_t)row * HID + col] = (_Float16)v;
            }
        }
    }
}

// ---------------- combine the two weighted expert rows per token ----------------
__global__ __launch_bounds__(256) void k_combine(const _Float16* __restrict__ yb,
                                                 const int* __restrict__ tslot,
                                                 float* __restrict__ out) {
    int t = blockIdx.x;
    int s0 = tslot[2 * t], s1 = tslot[2 * t + 1];
    int c = threadIdx.x * 8;
    half8 y0 = *(const half8*)&yb[(size_t)s0 * HID + c];
    half8 y1 = *(const half8*)&yb[(size_t)s1 * HID + c];
    float* op = out + (size_t)t * HID + c;
    float4 o;
    o.x = (float)y0[0] + (float)y1[0];
    o.y = (float)y0[1] + (float)y1[1];
    o.z = (float)y0[2] + (float)y1[2];
    o.w = (float)y0[3] + (float)y1[3];
    *(float4*)(op) = o;
    o.x = (float)y0[4] + (float)y1[4];
    o.y = (float)y0[5] + (float)y1[5];
    o.z = (float)y0[6] + (float)y1[6];
    o.w = (float)y0[7] + (float)y1[7];
    *(float4*)(op + 4) = o;
}

extern "C" void kernel_launch(void* const* d_in, const int* in_sizes, int n_in,
                              void* d_out, int out_size, void* d_ws, size_t ws_size,
                              hipStream_t stream) {
    const float* x  = (const float*)d_in[0];
    const float* Wg = (const float*)d_in[1];
    const float* bg = (const float*)d_in[2];
    const float* W1 = (const float*)d_in[3];
    const float* b1 = (const float*)d_in[4];
    const float* W2 = (const float*)d_in[5];
    const float* b2 = (const float*)d_in[6];
    float* out = (float*)d_out;

    // ws layout (yb aliases xh+w1t, both dead by gemm2)
    char* ws = (char*)d_ws;
    _Float16* xh  = (_Float16*)(ws);
    _Float16* yb  = (_Float16*)(ws);                        // alias: safe, see order
    _Float16* w1t = (_Float16*)(ws + 33554432ULL);
    _Float16* w2t = (_Float16*)(ws + 100663296ULL);
    _Float16* hb  = (_Float16*)(ws + 167772160ULL);
    char* rt = ws + 167772160ULL + (size_t)ARENA * HID * 2; // 243,269,632
    int*   counts = (int*)(rt);              // 8
    int*   poff   = (int*)(rt + 64);         // 9
    int*   cj     = (int*)(rt + 128);        // 9
    int*   te     = (int*)(rt + 192);        // 16384 ints
    float* tw     = (float*)(rt + 192 + 65536);
    int*   tslot  = (int*)(rt + 192 + 131072);
    int*   ltok   = (int*)(rt + 192 + 196608);              // ARENA ints
    float* lw     = (float*)(rt + 192 + 196608 + 73728);    // ARENA floats

    hipMemsetAsync(rt, 0, 64, stream);                   // counts
    hipMemsetAsync(ltok, 0, (size_t)ARENA * 8, stream);  // ltok + lw pads = 0
    k_prep_gate<<<dim3(8704), 256, 0, stream>>>(W1, w1t, x, Wg, bg, xh, te, tw, counts);
    k_route<<<1, 256, 0, stream>>>(counts, poff, cj, te, tw, ltok, lw, tslot);
    k_gemm<1><<<dim3(NJOBS + 8192), 256, 0, stream>>>(xh, w1t, b1, cj, poff, ltok,
                                                      nullptr, W2, w2t, hb);
    k_gemm<2><<<dim3(NJOBS), 256, 0, stream>>>(hb, w2t, b2, cj, poff, ltok, lw,
                                               nullptr, nullptr, yb);
    k_combine<<<8192, 256, 0, stream>>>(yb, tslot, out);
}